// Round 6
// baseline (133.273 us; speedup 1.0000x reference)
//
#include <hip/hip_runtime.h>
#include <math.h>

#define BATCH 16384

typedef float v2f __attribute__((ext_vector_type(2)));
typedef unsigned short u16;
typedef __attribute__((ext_vector_type(8))) short short8;
typedef __attribute__((ext_vector_type(4))) float f32x4;

__device__ __forceinline__ v2f pk_fma(v2f a, v2f b, v2f c) {
  return __builtin_elementwise_fma(a, b, c);   // -> v_pk_fma_f32
}
__device__ __forceinline__ v2f pk_max(v2f a, v2f b) {
  return __builtin_elementwise_max(a, b);      // -> v_pk_max_f32
}

// RNE-pack two floats into a bf16 pair (lo -> low16, hi -> high16)
__device__ __forceinline__ unsigned bf2(float lo, float hi) {
  unsigned a = __float_as_uint(lo);
  unsigned b = __float_as_uint(hi);
  a = (a + 0x7fffu + ((a >> 16) & 1u)) >> 16;
  b = (b + 0x7fffu + ((b >> 16) & 1u)) & 0xffff0000u;
  return a | b;
}

// single-inst RNE pack: dst.lo16 = bf16(lo), dst.hi16 = bf16(hi)
__device__ __forceinline__ unsigned cvtpk(float lo, float hi) {
  unsigned r;
  asm("v_cvt_pk_bf16_f32 %0, %1, %2" : "=v"(r) : "v"(lo), "v"(hi));
  return r;
}

// v17 = v16 with conv2-MFMA re-shaped for occupancy. v16 issue accounting:
// conv1 at VALU floor, conv2/linear on MFMA, but LDS 49.7KB -> 3 blocks/CU
// and ~40% of wall is latency bubbles. Re-shape conv2 M: 16 = 4 round-samples
// x 4 positions, processed per round (conv1 one sample/wave -> 2KB h1cur[w];
// barrier; block-cooperative conv2 over 13 position-groups; barrier). Same
// MFMA/read/epilogue counts as v16, LDS 24.4KB -> 6 blocks/CU (2x occupancy
// ceiling) at the cost of 6 extra barriers. C-row encoding row=4*ps+ms keeps
// all stores static-indexed. Pad positions 49..51 read in-allocation garbage,
// never stored.
__global__ __launch_bounds__(256) void qnat_fused(
    const float* __restrict__ x,    // (B,1,28,28)
    const float* __restrict__ w1,   // (4,1,3,3)  uniform -> s_load
    const float* __restrict__ b1,   // (4,)
    const float* __restrict__ w2,   // (4,4,3,3)  uniform -> s_load
    const float* __restrict__ b2,   // (4,)
    const float* __restrict__ plw,  // (16,196)
    const float* __restrict__ plb,  // (16,)
    const float* __restrict__ rw,   // (4,4)
    const float* __restrict__ rb,   // (4,)
    float* __restrict__ pre,        // (B,4) pre-BN output (in d_out)
    float* __restrict__ stats)      // [8] {sum_c, sumsq_c}
{
  // per-wave, per-round conv1 output (1 sample) bf16: 4ci x 16x16 u16
  // (+1 pad dword -> stride 513 dwords: sample-strided gathers spread banks)
  __shared__ __align__(16) unsigned h1cur[4][513];
  // block-shared h2 (bf16): 16 slots; 196 data + pad to 224 + 8 -> stride 232
  __shared__ __align__(16) u16 h2b[16][232];
  // transposed bf16 plw in B-fragment layout; rows 25..27 zero (K pad 224)
  __shared__ __align__(16) uint4 plw_tb[28 * 16];
  // conv2 B fragments: b2ft[h*64 + g*16 + n] = short8 of K-slots 32h+8g..+7
  // for col n; slot s = ci*16+dy*4+dx, B[s][n] = w2[co][dy-sy][dx-sx] or 0
  __shared__ __align__(16) short8 b2ft[128];
  __shared__ float s_red[4][8];

  const int tid = threadIdx.x;
  const int w = tid >> 6;
  const int lane = tid & 63;
  const int base = (blockIdx.x * 4 + w) * 4;    // first of 4 samples

  // ---- stage plw -> plw_tb (bf16, transposed), once per block ----
  #pragma unroll
  for (int j = 0; j < 2; j++) {
    int s = tid + 256 * j;
    if (s < 448) {
      int tp = s >> 4;                // 0..27
      int k2 = s & 15;
      uint4 v = make_uint4(0u, 0u, 0u, 0u);
      if (tp < 25) {
        const float4* pr = (const float4*)(plw + k2 * 196);
        float4 a = pr[2 * tp];
        float4 b = (tp < 24) ? pr[2 * tp + 1] : make_float4(0.f, 0.f, 0.f, 0.f);
        v = make_uint4(bf2(a.x, a.y), bf2(a.z, a.w),
                       bf2(b.x, b.y), bf2(b.z, b.w));
      }
      plw_tb[s] = v;
    }
  }

  // ---- build conv2 B fragments (128 short8, threads 0..127) ----
  if (tid < 128) {
    int h = tid >> 6, g = (tid >> 4) & 3, n = tid & 15;
    int co = n >> 2, sy = (n >> 1) & 1, sx = n & 1;
    short8 bv;
    #pragma unroll
    for (int j = 0; j < 8; j++) {
      int s = 32 * h + 8 * g + j;
      int ci = s >> 4, dy = (s >> 2) & 3, dx = s & 3;
      int ry = dy - sy, rx = dx - sx;
      float v = 0.0f;
      if (ry >= 0 && ry < 3 && rx >= 0 && rx < 3)
        v = w2[((co * 4 + ci) * 3 + ry) * 3 + rx];
      bv[j] = (short)(u16)bf2(v, 0.0f);
    }
    b2ft[tid] = bv;
  }

  // ---- zero h1cur (pads persist) + h2b fully ----
  {
    uint4 z4 = make_uint4(0u, 0u, 0u, 0u);
    uint4* hz = (uint4*)h1cur;                  // 4*513 dwords = 513 uint4
    #pragma unroll
    for (int t = 0; t < 3; t++) {
      int p = tid + 256 * t;
      if (p < 513) hz[p] = z4;
    }
    uint4* hz2 = (uint4*)h2b;                   // 16*232 shorts = 464 uint4
    #pragma unroll
    for (int t = 0; t < 2; t++) {
      int p = tid + 256 * t;
      if (p < 464) hz2[p] = z4;
    }
  }
  __syncthreads();   // plw_tb, b2ft, zeros visible

  const int i = lane >> 2;            // conv1: pooled row 0..13
  const int q = lane & 3;             // conv1: col quad
  const bool c1act = lane < 56;

  // prefetch buffers for conv1 windows (cols 8q-1 .. 8q+8 fully covered)
  float4 pfa[4], pfb[4];
  float pe0[4], pe1[4];
  #pragma unroll
  for (int r = 0; r < 4; r++) {
    pfa[r] = make_float4(0,0,0,0); pfb[r] = make_float4(0,0,0,0);
    pe0[r] = 0.0f; pe1[r] = 0.0f;
  }

  if (c1act) {
    const float* xb = x + (size_t)base * 784;
    #pragma unroll
    for (int r = 0; r < 4; r++) {
      int row = 2 * i - 1 + r;
      if (0 <= row && row < 28) {
        const float* rp = xb + row * 28;
        pfa[r] = *(const float4*)(rp + 8 * q);
        if (q > 0) pe0[r] = rp[8 * q - 1];
        if (q < 3) {
          pfb[r] = *(const float4*)(rp + 8 * q + 4);
          pe1[r] = rp[8 * q + 8];
        }
      }
    }
  }

  // ============ stage 1: 4 rounds of {conv1 -> barrier -> conv2} ============
  #pragma unroll 1
  for (int it = 0; it < 4; ++it) {
    // ---- conv1 + relu + pool -> h1cur[w] (bf16), sample 4w+it ----
    if (c1act) {
      float win[4][10];               // win[r][k] <-> input col 8q-1+k
      #pragma unroll
      for (int r = 0; r < 4; r++) {
        win[r][0] = pe0[r];
        win[r][1] = pfa[r].x; win[r][2] = pfa[r].y;
        win[r][3] = pfa[r].z; win[r][4] = pfa[r].w;
        win[r][5] = pfb[r].x; win[r][6] = pfb[r].y;
        win[r][7] = pfb[r].z; win[r][8] = pfb[r].w;
        win[r][9] = pe1[r];
      }
      // prefetch next sample's rows while conv1 FMAs run
      if (it != 3) {
        const float* xn = x + (size_t)(base + it + 1) * 784;
        #pragma unroll
        for (int r = 0; r < 4; r++) {
          int row = 2 * i - 1 + r;
          pfa[r] = make_float4(0,0,0,0);
          pfb[r] = make_float4(0,0,0,0);
          pe0[r] = 0.0f; pe1[r] = 0.0f;
          if (0 <= row && row < 28) {
            const float* rp = xn + row * 28;
            pfa[r] = *(const float4*)(rp + 8 * q);
            if (q > 0) pe0[r] = rp[8 * q - 1];
            if (q < 3) {
              pfb[r] = *(const float4*)(rp + 8 * q + 4);
              pe1[r] = rp[8 * q + 8];
            }
          }
        }
      }
      v2f P[4][9];
      #pragma unroll
      for (int r = 0; r < 4; r++)
        #pragma unroll
        for (int k = 0; k < 9; k++) P[r][k] = (v2f){win[r][k], win[r][k + 1]};

      u16* hs = (u16*)&h1cur[w][0] + (i + 1) * 16 + 4 * q;
      #pragma unroll
      for (int c = 0; c < 4; c++) {
        const float* wc = w1 + c * 9;
        const v2f bias2 = (v2f){b1[c], b1[c]};
        v2f a0[4], a1[4];
        #pragma unroll
        for (int jj = 0; jj < 4; jj++) { a0[jj] = bias2; a1[jj] = bias2; }
        #pragma unroll
        for (int dy = 0; dy < 3; dy++)
          #pragma unroll
          for (int dx = 0; dx < 3; dx++) {
            const float wv = wc[dy * 3 + dx];
            const v2f wvv = (v2f){wv, wv};
            #pragma unroll
            for (int jj = 0; jj < 4; jj++) {
              a0[jj] = pk_fma(P[dy][2 * jj + dx],     wvv, a0[jj]);
              a1[jj] = pk_fma(P[dy + 1][2 * jj + dx], wvv, a1[jj]);
            }
          }
        float m[4];
        #pragma unroll
        for (int jj = 0; jj < 4; jj++) {
          v2f mm = pk_max(a0[jj], a1[jj]);
          m[jj] = fmaxf(fmaxf(mm.x, mm.y), 0.0f);
        }
        u16* p = hs + c * 256;        // stored cols 4q+1 .. 4q+4
        p[1] = (u16)cvtpk(m[0], m[0]);
        if (q < 3) {
          *(unsigned*)(p + 2) = cvtpk(m[1], m[2]);   // even u16 idx, 4B align
          p[4] = (u16)cvtpk(m[3], m[3]);
        } else {
          p[2] = (u16)cvtpk(m[1], m[1]);
        }
      }
    }
    __syncthreads();   // h1cur[0..3] complete for round it

    // ---- conv2 + relu + pool via MFMA: M=16 = 4 samples x 4 positions ----
    {
      const int n2 = lane & 15;       // C col = (co, sy, sx)
      const int g2 = lane >> 4;       // k-group; C rows 4*g2..4*g2+3
      short8 bfr0 = b2ft[g2 * 16 + n2];
      short8 bfr1 = b2ft[64 + g2 * 16 + n2];
      const float bias = b2[n2 >> 2];
      const int msA = lane & 3;           // A row: sample ms = row&3
      const int psA = (lane >> 2) & 3;    // A row: pos-in-group ps = row>>2
      const int ciA = g2 >> 1;            // first-MFMA input channel
      const int dy0 = 2 * (g2 & 1);
      const unsigned* h1 = &h1cur[0][0];

      for (int G = w; G < 13; G += 4) {   // groups: positions 4G..4G+3
        int p = 4 * G + psA;
        int i2 = (p * 9363) >> 16;        // p/7 (p<=51)
        int j2 = p - 7 * i2;
        int a = msA * 513 + ciA * 128 + (2 * i2 + dy0) * 8 + j2;
        unsigned A0 = h1[a],       A1 = h1[a + 1];
        unsigned A2 = h1[a + 8],   A3 = h1[a + 9];
        short8 av0 = __builtin_bit_cast(short8, make_uint4(A0, A1, A2, A3));
        unsigned B0 = h1[a + 256], B1 = h1[a + 257];
        unsigned B2 = h1[a + 264], B3 = h1[a + 265];
        short8 av1 = __builtin_bit_cast(short8, make_uint4(B0, B1, B2, B3));
        f32x4 acc = {bias, bias, bias, bias};
        acc = __builtin_amdgcn_mfma_f32_16x16x32_bf16(av0, bfr0, acc, 0, 0, 0);
        acc = __builtin_amdgcn_mfma_f32_16x16x32_bf16(av1, bfr1, acc, 0, 0, 0);
        // pool over sx (col^1), sy (col^2); rows: ps = g2, ms = reg
        float r0 = acc[0], r1 = acc[1], r2 = acc[2], r3 = acc[3];
        r0 = fmaxf(r0, __shfl_xor(r0, 1, 64)); r0 = fmaxf(r0, __shfl_xor(r0, 2, 64));
        r1 = fmaxf(r1, __shfl_xor(r1, 1, 64)); r1 = fmaxf(r1, __shfl_xor(r1, 2, 64));
        r2 = fmaxf(r2, __shfl_xor(r2, 1, 64)); r2 = fmaxf(r2, __shfl_xor(r2, 2, 64));
        r3 = fmaxf(r3, __shfl_xor(r3, 1, 64)); r3 = fmaxf(r3, __shfl_xor(r3, 2, 64));
        int pst = 4 * G + g2;             // this lane's stored position
        if ((lane & 3) == 0 && pst < 49) {
          int off = 49 * (n2 >> 2) + pst;
          float v0 = fmaxf(r0, 0.0f);
          float v1 = fmaxf(r1, 0.0f);
          float v2 = fmaxf(r2, 0.0f);
          float v3 = fmaxf(r3, 0.0f);
          h2b[it][off]      = (u16)cvtpk(v0, v0);   // sample slot it
          h2b[4 + it][off]  = (u16)cvtpk(v1, v1);   // slot 4+it
          h2b[8 + it][off]  = (u16)cvtpk(v2, v2);   // slot 8+it
          h2b[12 + it][off] = (u16)cvtpk(v3, v3);   // slot 12+it
        }
      }
    }
    __syncthreads();   // conv2 reads done; h1cur reusable next round
  }

  // ============ stage 2: MFMA linear + circuit for all 4 samples ============
  const int s2 = lane >> 4;           // sample slot 0..3 (within wave)
  const int k = lane & 15;            // param index / amp index

  // ---- linear: 16x224 @ 224x16 bf16 GEMM, 7 MFMA, all waves redundant ----
  float cv, sv;
  {
    const int arow = lane & 15;       // A row = block sample slot, B col = param
    const int kg = lane >> 4;         // k-group 0..3 (8 bf16 each)
    const short8* ha = (const short8*)&h2b[arow][0];    // 29 short8 per slot
    const short8* hbw = (const short8*)plw_tb;
    f32x4 acc = {0.f, 0.f, 0.f, 0.f};
    #pragma unroll
    for (int kt = 0; kt < 7; kt++) {
      short8 av = ha[4 * kt + kg];
      short8 bv = hbw[(4 * kt + kg) * 16 + arow];
      acc = __builtin_amdgcn_mfma_f32_16x16x32_bf16(av, bv, acc, 0, 0, 0);
    }
    // C[row=4*(l>>4)+reg][col=l&15]; wave w needs rows 4w..4w+3 -> quadrant w.
    const int srcl = 16 * w + k;      // lane holding C[4w+*][k]
    float c0 = __shfl(acc[0], srcl, 64);
    float c1 = __shfl(acc[1], srcl, 64);
    float c2 = __shfl(acc[2], srcl, 64);
    float c3 = __shfl(acc[3], srcl, 64);
    float pv = (s2 & 2) ? ((s2 & 1) ? c3 : c2) : ((s2 & 1) ? c1 : c0);
    pv += plb[k];
    __sincosf(pv * 0.5f, &sv, &cv);
  }

  // ---- 4-qubit circuit: 4 samples in parallel on 16-lane groups ----
  {
    const int l = k;                  // amp index within group
    const int gb = lane & 48;         // group base for param broadcasts
    float re = (l == 0) ? 1.0f : 0.0f;
    float im = 0.0f;
    #pragma unroll
    for (int qi = 0; qi < 4; qi++) {
      const int beta = 3 - qi;
      const int m = 1 << beta;        // <16: shfl_xor stays in group
      const int b = (l >> beta) & 1;
      float c = __shfl(cv, gb + 4 * qi, 64), s = __shfl(sv, gb + 4 * qi, 64);
      float pr_ = __shfl_xor(re, m, 64), pi_ = __shfl_xor(im, m, 64);
      float sg = b ? s : -s;
      re = fmaf(c, re, sg * pr_);
      im = fmaf(c, im, sg * pi_);
      c = __shfl(cv, gb + 4 * qi + 1, 64); s = __shfl(sv, gb + 4 * qi + 1, 64);
      float sz = b ? s : -s;
      float nr = c * re - sz * im;
      float ni = c * im + sz * re;
      re = nr; im = ni;
      c = __shfl(cv, gb + 4 * qi + 2, 64); s = __shfl(sv, gb + 4 * qi + 2, 64);
      pr_ = __shfl_xor(re, m, 64); pi_ = __shfl_xor(im, m, 64);
      nr = fmaf(c, re, s * pi_);
      ni = fmaf(c, im, -s * pr_);
      re = nr; im = ni;
      const int tm = 1 << (3 - ((qi + 1) & 3));   // <16: in-group
      float fr = __shfl_xor(re, tm, 64), fi = __shfl_xor(im, tm, 64);
      if (b) { re = fr; im = fi; }
    }
    float pr2 = re * re + im * im;
    float z0 = ((l >> 3) & 1) ? -pr2 : pr2;
    float z1 = ((l >> 2) & 1) ? -pr2 : pr2;
    float z2 = ((l >> 1) & 1) ? -pr2 : pr2;
    float z3 = (l & 1) ? -pr2 : pr2;
    #pragma unroll
    for (int off = 8; off >= 1; off >>= 1) {      // in-group reductions
      z0 += __shfl_xor(z0, off, 64);
      z1 += __shfl_xor(z1, off, 64);
      z2 += __shfl_xor(z2, off, 64);
      z3 += __shfl_xor(z3, off, 64);
    }
    float as0 = 0.f, as1 = 0.f, as2 = 0.f, as3 = 0.f;
    float aq0 = 0.f, aq1 = 0.f, aq2 = 0.f, aq3 = 0.f;
    if (l == 0) {                     // lanes 0,16,32,48: one sample each
      float o0 = fmaf(rw[0],  z0, fmaf(rw[1],  z1, fmaf(rw[2],  z2, fmaf(rw[3],  z3, rb[0]))));
      float o1 = fmaf(rw[4],  z0, fmaf(rw[5],  z1, fmaf(rw[6],  z2, fmaf(rw[7],  z3, rb[1]))));
      float o2 = fmaf(rw[8],  z0, fmaf(rw[9],  z1, fmaf(rw[10], z2, fmaf(rw[11], z3, rb[2]))));
      float o3 = fmaf(rw[12], z0, fmaf(rw[13], z1, fmaf(rw[14], z2, fmaf(rw[15], z3, rb[3]))));
      *(float4*)(pre + (size_t)(base + s2) * 4) = make_float4(o0, o1, o2, o3);
      as0 = o0; aq0 = o0 * o0;
      as1 = o1; aq1 = o1 * o1;
      as2 = o2; aq2 = o2 * o2;
      as3 = o3; aq3 = o3 * o3;
    }
    #pragma unroll
    for (int off = 32; off >= 16; off >>= 1) {
      as0 += __shfl_down(as0, off, 64); aq0 += __shfl_down(aq0, off, 64);
      as1 += __shfl_down(as1, off, 64); aq1 += __shfl_down(aq1, off, 64);
      as2 += __shfl_down(as2, off, 64); aq2 += __shfl_down(aq2, off, 64);
      as3 += __shfl_down(as3, off, 64); aq3 += __shfl_down(aq3, off, 64);
    }
    if (lane == 0) {
      s_red[w][0] = as0; s_red[w][4] = aq0;
      s_red[w][1] = as1; s_red[w][5] = aq1;
      s_red[w][2] = as2; s_red[w][6] = aq2;
      s_red[w][3] = as3; s_red[w][7] = aq3;
    }
  }
  __syncthreads();
  if (tid < 8) {
    float v = s_red[0][tid] + s_red[1][tid] + s_red[2][tid] + s_red[3][tid];
    atomicAdd(&stats[tid], v);
  }
}

__global__ __launch_bounds__(256) void qnat_bn(
    float* __restrict__ pre,
    const float* __restrict__ stats,
    const float* __restrict__ bnw,
    const float* __restrict__ bnb)
{
  int idx = blockIdx.x * 256 + threadIdx.x;
  int c = idx & 3;
  float mean = stats[c] * (1.0f / BATCH);
  float ex2 = stats[4 + c] * (1.0f / BATCH);
  float var = ex2 - mean * mean;
  float inv = rsqrtf(var + 1e-5f);
  pre[idx] = (pre[idx] - mean) * inv * bnw[c] + bnb[c];
}

extern "C" void kernel_launch(void* const* d_in, const int* in_sizes, int n_in,
                              void* d_out, int out_size, void* d_ws, size_t ws_size,
                              hipStream_t stream) {
  const float* x   = (const float*)d_in[0];
  const float* w1  = (const float*)d_in[1];
  const float* b1  = (const float*)d_in[2];
  const float* w2  = (const float*)d_in[3];
  const float* b2  = (const float*)d_in[4];
  const float* plw = (const float*)d_in[5];
  const float* plb = (const float*)d_in[6];
  const float* rw  = (const float*)d_in[7];
  const float* rb  = (const float*)d_in[8];
  const float* bnw = (const float*)d_in[9];
  const float* bnb = (const float*)d_in[10];

  float* out   = (float*)d_out;
  float* stats = (float*)d_ws;

  hipMemsetAsync(stats, 0, 8 * sizeof(float), stream);
  qnat_fused<<<BATCH / 16, 256, 0, stream>>>(x, w1, b1, w2, b2, plw, plb, rw, rb, out, stats);
  qnat_bn<<<(BATCH * 4) / 256, 256, 0, stream>>>(out, stats, bnw, bnb);
}

// Round 7
// 131.041 us; speedup vs baseline: 1.0170x; 1.0170x over previous
//
#include <hip/hip_runtime.h>
#include <math.h>

#define BATCH 16384

typedef float v2f __attribute__((ext_vector_type(2)));
typedef unsigned short u16;
typedef __attribute__((ext_vector_type(8))) short short8;
typedef __attribute__((ext_vector_type(4))) float f32x4;

__device__ __forceinline__ v2f pk_fma(v2f a, v2f b, v2f c) {
  return __builtin_elementwise_fma(a, b, c);   // -> v_pk_fma_f32
}
__device__ __forceinline__ v2f pk_max(v2f a, v2f b) {
  return __builtin_elementwise_max(a, b);      // -> v_pk_max_f32
}

// RNE-pack two floats into a bf16 pair (lo -> low16, hi -> high16)
__device__ __forceinline__ unsigned bf2(float lo, float hi) {
  unsigned a = __float_as_uint(lo);
  unsigned b = __float_as_uint(hi);
  a = (a + 0x7fffu + ((a >> 16) & 1u)) >> 16;
  b = (b + 0x7fffu + ((b >> 16) & 1u)) & 0xffff0000u;
  return a | b;
}

// single-inst RNE pack: dst.lo16 = bf16(lo), dst.hi16 = bf16(hi)
__device__ __forceinline__ unsigned cvtpk(float lo, float hi) {
  unsigned r;
  asm("v_cvt_pk_bf16_f32 %0, %1, %2" : "=v"(r) : "v"(lo), "v"(hi));
  return r;
}

// v18 = v16 with conv2-MFMA re-decomposed as M = 16 POSITIONS x 1 sample
// (4 groups cover 49 pooled positions). This makes conv2 wave-private:
// conv1 sample -> 2.2KB wave-private h1cur[w] -> immediate MFMA, no stage-1
// barriers at all (v16 had 1, v17's 6 barriers regressed). LDS 49.7->25.9KB
// removes v16's residency tail (3 blocks/CU vs 4 needed). v17 lessons: VGPR
// must stay <=~76 (B-frags reloaded per round, not held), occupancy is
// VGPR-capped at 16 waves/CU - stop chasing it. MFMA/wave 26->32 (idle pipe).
// Fragment conventions + A-address formula verified by v16/v17 refchecks.
__global__ __launch_bounds__(256) void qnat_fused(
    const float* __restrict__ x,    // (B,1,28,28)
    const float* __restrict__ w1,   // (4,1,3,3)  uniform -> s_load
    const float* __restrict__ b1,   // (4,)
    const float* __restrict__ w2,   // (4,4,3,3)  uniform -> s_load
    const float* __restrict__ b2,   // (4,)
    const float* __restrict__ plw,  // (16,196)
    const float* __restrict__ plb,  // (16,)
    const float* __restrict__ rw,   // (4,4)
    const float* __restrict__ rb,   // (4,)
    float* __restrict__ pre,        // (B,4) pre-BN output (in d_out)
    float* __restrict__ stats)      // [8] {sum_c, sumsq_c}
{
  // per-wave conv1 output (1 sample) bf16: 4ci x 16x16 u16 = 512 dwords,
  // padded to 560 so pad-position A-reads (p up to 63) stay in-bounds (zeros).
  __shared__ __align__(16) unsigned h1cur[4][560];
  // block-shared h2 (bf16): 16 slots; 196 data + pad to 224 + 8 -> stride 232
  __shared__ __align__(16) u16 h2b[16][232];
  // transposed bf16 plw in B-fragment layout; rows 25..27 zero (K pad 224)
  __shared__ __align__(16) uint4 plw_tb[28 * 16];
  // conv2 B fragments: b2ft[h*64 + g*16 + n] = short8 of K-slots 32h+8g..+7
  // for col n; slot s = ci*16+dy*4+dx, B[s][n] = w2[co][dy-sy][dx-sx] or 0
  __shared__ __align__(16) short8 b2ft[128];
  __shared__ float s_red[4][8];

  const int tid = threadIdx.x;
  const int w = tid >> 6;
  const int lane = tid & 63;
  const int base = (blockIdx.x * 4 + w) * 4;    // first of 4 samples

  // ---- stage plw -> plw_tb (bf16, transposed), once per block ----
  #pragma unroll
  for (int j = 0; j < 2; j++) {
    int s = tid + 256 * j;
    if (s < 448) {
      int tp = s >> 4;                // 0..27
      int k2 = s & 15;
      uint4 v = make_uint4(0u, 0u, 0u, 0u);
      if (tp < 25) {
        const float4* pr = (const float4*)(plw + k2 * 196);
        float4 a = pr[2 * tp];
        float4 b = (tp < 24) ? pr[2 * tp + 1] : make_float4(0.f, 0.f, 0.f, 0.f);
        v = make_uint4(bf2(a.x, a.y), bf2(a.z, a.w),
                       bf2(b.x, b.y), bf2(b.z, b.w));
      }
      plw_tb[s] = v;
    }
  }

  // ---- build conv2 B fragments (128 short8, threads 0..127) ----
  if (tid < 128) {
    int h = tid >> 6, g = (tid >> 4) & 3, n = tid & 15;
    int co = n >> 2, sy = (n >> 1) & 1, sx = n & 1;
    short8 bv;
    #pragma unroll
    for (int j = 0; j < 8; j++) {
      int s = 32 * h + 8 * g + j;
      int ci = s >> 4, dy = (s >> 2) & 3, dx = s & 3;
      int ry = dy - sy, rx = dx - sx;
      float v = 0.0f;
      if (ry >= 0 && ry < 3 && rx >= 0 && rx < 3)
        v = w2[((co * 4 + ci) * 3 + ry) * 3 + rx];
      bv[j] = (short)(u16)bf2(v, 0.0f);
    }
    b2ft[tid] = bv;
  }

  // ---- zero h1cur fully (pads persist) + h2b fully ----
  {
    uint4 z4 = make_uint4(0u, 0u, 0u, 0u);
    uint4* hz = (uint4*)h1cur;                  // 4*560 dwords = 560 uint4
    #pragma unroll
    for (int t = 0; t < 3; t++) {
      int p = tid + 256 * t;
      if (p < 560) hz[p] = z4;
    }
    uint4* hz2 = (uint4*)h2b;                   // 16*232 shorts = 464 uint4
    #pragma unroll
    for (int t = 0; t < 2; t++) {
      int p = tid + 256 * t;
      if (p < 464) hz2[p] = z4;
    }
  }
  __syncthreads();   // plw_tb, b2ft, zeros visible

  const int i = lane >> 2;            // conv1: pooled row 0..13
  const int q = lane & 3;             // conv1: col quad
  const bool c1act = lane < 56;

  // prefetch buffers for conv1 windows (cols 8q-1 .. 8q+8 fully covered)
  float4 pfa[4], pfb[4];
  float pe0[4], pe1[4];
  #pragma unroll
  for (int r = 0; r < 4; r++) {
    pfa[r] = make_float4(0,0,0,0); pfb[r] = make_float4(0,0,0,0);
    pe0[r] = 0.0f; pe1[r] = 0.0f;
  }

  if (c1act) {
    const float* xb = x + (size_t)base * 784;
    #pragma unroll
    for (int r = 0; r < 4; r++) {
      int row = 2 * i - 1 + r;
      if (0 <= row && row < 28) {
        const float* rp = xb + row * 28;
        pfa[r] = *(const float4*)(rp + 8 * q);
        if (q > 0) pe0[r] = rp[8 * q - 1];
        if (q < 3) {
          pfb[r] = *(const float4*)(rp + 8 * q + 4);
          pe1[r] = rp[8 * q + 8];
        }
      }
    }
  }

  // ===== stage 1: 4 rounds of {conv1 -> conv2}, fully wave-private =========
  #pragma unroll 1
  for (int it = 0; it < 4; ++it) {
    // ---- conv1 + relu + pool -> h1cur[w] (bf16), sample base+it ----
    if (c1act) {
      float win[4][10];               // win[r][k] <-> input col 8q-1+k
      #pragma unroll
      for (int r = 0; r < 4; r++) {
        win[r][0] = pe0[r];
        win[r][1] = pfa[r].x; win[r][2] = pfa[r].y;
        win[r][3] = pfa[r].z; win[r][4] = pfa[r].w;
        win[r][5] = pfb[r].x; win[r][6] = pfb[r].y;
        win[r][7] = pfb[r].z; win[r][8] = pfb[r].w;
        win[r][9] = pe1[r];
      }
      // prefetch next sample's rows while conv1 FMAs run
      if (it != 3) {
        const float* xn = x + (size_t)(base + it + 1) * 784;
        #pragma unroll
        for (int r = 0; r < 4; r++) {
          int row = 2 * i - 1 + r;
          pfa[r] = make_float4(0,0,0,0);
          pfb[r] = make_float4(0,0,0,0);
          pe0[r] = 0.0f; pe1[r] = 0.0f;
          if (0 <= row && row < 28) {
            const float* rp = xn + row * 28;
            pfa[r] = *(const float4*)(rp + 8 * q);
            if (q > 0) pe0[r] = rp[8 * q - 1];
            if (q < 3) {
              pfb[r] = *(const float4*)(rp + 8 * q + 4);
              pe1[r] = rp[8 * q + 8];
            }
          }
        }
      }
      v2f P[4][9];
      #pragma unroll
      for (int r = 0; r < 4; r++)
        #pragma unroll
        for (int k = 0; k < 9; k++) P[r][k] = (v2f){win[r][k], win[r][k + 1]};

      u16* hs = (u16*)&h1cur[w][0] + (i + 1) * 16 + 4 * q;
      #pragma unroll
      for (int c = 0; c < 4; c++) {
        const float* wc = w1 + c * 9;
        const v2f bias2 = (v2f){b1[c], b1[c]};
        v2f a0[4], a1[4];
        #pragma unroll
        for (int jj = 0; jj < 4; jj++) { a0[jj] = bias2; a1[jj] = bias2; }
        #pragma unroll
        for (int dy = 0; dy < 3; dy++)
          #pragma unroll
          for (int dx = 0; dx < 3; dx++) {
            const float wv = wc[dy * 3 + dx];
            const v2f wvv = (v2f){wv, wv};
            #pragma unroll
            for (int jj = 0; jj < 4; jj++) {
              a0[jj] = pk_fma(P[dy][2 * jj + dx],     wvv, a0[jj]);
              a1[jj] = pk_fma(P[dy + 1][2 * jj + dx], wvv, a1[jj]);
            }
          }
        float m[4];
        #pragma unroll
        for (int jj = 0; jj < 4; jj++) {
          v2f mm = pk_max(a0[jj], a1[jj]);
          m[jj] = fmaxf(fmaxf(mm.x, mm.y), 0.0f);
        }
        u16* p = hs + c * 256;        // stored cols 4q+1 .. 4q+4
        p[1] = (u16)cvtpk(m[0], m[0]);
        if (q < 3) {
          *(unsigned*)(p + 2) = cvtpk(m[1], m[2]);   // even u16 idx, 4B align
          p[4] = (u16)cvtpk(m[3], m[3]);
        } else {
          p[2] = (u16)cvtpk(m[1], m[1]);
        }
      }
    }
    // h1cur[w] wave-private: no barrier (compiler orders via lgkmcnt).

    // ---- conv2 + relu + pool via MFMA: M = 16 positions, this sample ----
    {
      const int n2 = lane & 15;       // A row = pos-in-group, B/C col = (co,sy,sx)
      const int g2 = lane >> 4;       // k-group
      const short8 bfr0 = b2ft[g2 * 16 + n2];        // reload per round (VGPR)
      const short8 bfr1 = b2ft[64 + g2 * 16 + n2];
      const float bias = b2[n2 >> 2];
      const int ciA = g2 >> 1;
      const int dy0 = 2 * (g2 & 1);
      const unsigned* h1 = &h1cur[w][0];
      u16* hq = &h2b[4 * w + it][0];

      #pragma unroll
      for (int t = 0; t < 4; t++) {   // position groups 16t..16t+15
        int p = 16 * t + n2;
        int i2 = (p * 9363) >> 16;    // p/7 (p<=63)
        int j2 = p - 7 * i2;
        int a = ciA * 128 + (2 * i2 + dy0) * 8 + j2;
        unsigned A0 = h1[a],       A1 = h1[a + 1];
        unsigned A2 = h1[a + 8],   A3 = h1[a + 9];
        short8 av0 = __builtin_bit_cast(short8, make_uint4(A0, A1, A2, A3));
        unsigned B0 = h1[a + 256], B1 = h1[a + 257];
        unsigned B2 = h1[a + 264], B3 = h1[a + 265];
        short8 av1 = __builtin_bit_cast(short8, make_uint4(B0, B1, B2, B3));
        f32x4 acc = {bias, bias, bias, bias};
        acc = __builtin_amdgcn_mfma_f32_16x16x32_bf16(av0, bfr0, acc, 0, 0, 0);
        acc = __builtin_amdgcn_mfma_f32_16x16x32_bf16(av1, bfr1, acc, 0, 0, 0);
        // pool over sx (col^1), sy (col^2); C row = position-in-group
        float r0 = acc[0], r1 = acc[1], r2 = acc[2], r3 = acc[3];
        r0 = fmaxf(r0, __shfl_xor(r0, 1, 64)); r0 = fmaxf(r0, __shfl_xor(r0, 2, 64));
        r1 = fmaxf(r1, __shfl_xor(r1, 1, 64)); r1 = fmaxf(r1, __shfl_xor(r1, 2, 64));
        r2 = fmaxf(r2, __shfl_xor(r2, 1, 64)); r2 = fmaxf(r2, __shfl_xor(r2, 2, 64));
        r3 = fmaxf(r3, __shfl_xor(r3, 1, 64)); r3 = fmaxf(r3, __shfl_xor(r3, 2, 64));
        if ((lane & 3) == 0) {
          int co = n2 >> 2;
          int prow = 16 * t + 4 * g2;       // C rows prow..prow+3
          u16* hc = hq + 49 * co;
          if (prow < 49)     { float v0 = fmaxf(r0, 0.0f); hc[prow]     = (u16)cvtpk(v0, v0); }
          if (prow + 1 < 49) { float v1 = fmaxf(r1, 0.0f); hc[prow + 1] = (u16)cvtpk(v1, v1); }
          if (prow + 2 < 49) { float v2 = fmaxf(r2, 0.0f); hc[prow + 2] = (u16)cvtpk(v2, v2); }
          if (prow + 3 < 49) { float v3 = fmaxf(r3, 0.0f); hc[prow + 3] = (u16)cvtpk(v3, v3); }
        }
      }
    }
    // h2b slot 4w+it wave-owned: no barrier until stage 2.
  }
  __syncthreads();   // h2b complete for all 16 slots

  // ============ stage 2: MFMA linear + circuit for all 4 samples ============
  const int s2 = lane >> 4;           // sample slot 0..3 (within wave)
  const int k = lane & 15;            // param index / amp index

  // ---- linear: 16x224 @ 224x16 bf16 GEMM, 7 MFMA, all waves redundant ----
  float cv, sv;
  {
    const int arow = lane & 15;       // A row = block sample slot, B col = param
    const int kg = lane >> 4;         // k-group 0..3 (8 bf16 each)
    const short8* ha = (const short8*)&h2b[arow][0];    // 29 short8 per slot
    const short8* hbw = (const short8*)plw_tb;
    f32x4 acc = {0.f, 0.f, 0.f, 0.f};
    #pragma unroll
    for (int kt = 0; kt < 7; kt++) {
      short8 av = ha[4 * kt + kg];
      short8 bv = hbw[(4 * kt + kg) * 16 + arow];
      acc = __builtin_amdgcn_mfma_f32_16x16x32_bf16(av, bv, acc, 0, 0, 0);
    }
    // C[row=4*(l>>4)+reg][col=l&15]; wave w needs rows 4w..4w+3 -> quadrant w.
    const int srcl = 16 * w + k;      // lane holding C[4w+*][k]
    float c0 = __shfl(acc[0], srcl, 64);
    float c1 = __shfl(acc[1], srcl, 64);
    float c2 = __shfl(acc[2], srcl, 64);
    float c3 = __shfl(acc[3], srcl, 64);
    float pv = (s2 & 2) ? ((s2 & 1) ? c3 : c2) : ((s2 & 1) ? c1 : c0);
    pv += plb[k];
    __sincosf(pv * 0.5f, &sv, &cv);
  }

  // ---- 4-qubit circuit: 4 samples in parallel on 16-lane groups ----
  {
    const int l = k;                  // amp index within group
    const int gb = lane & 48;         // group base for param broadcasts
    float re = (l == 0) ? 1.0f : 0.0f;
    float im = 0.0f;
    #pragma unroll
    for (int qi = 0; qi < 4; qi++) {
      const int beta = 3 - qi;
      const int m = 1 << beta;        // <16: shfl_xor stays in group
      const int b = (l >> beta) & 1;
      float c = __shfl(cv, gb + 4 * qi, 64), s = __shfl(sv, gb + 4 * qi, 64);
      float pr_ = __shfl_xor(re, m, 64), pi_ = __shfl_xor(im, m, 64);
      float sg = b ? s : -s;
      re = fmaf(c, re, sg * pr_);
      im = fmaf(c, im, sg * pi_);
      c = __shfl(cv, gb + 4 * qi + 1, 64); s = __shfl(sv, gb + 4 * qi + 1, 64);
      float sz = b ? s : -s;
      float nr = c * re - sz * im;
      float ni = c * im + sz * re;
      re = nr; im = ni;
      c = __shfl(cv, gb + 4 * qi + 2, 64); s = __shfl(sv, gb + 4 * qi + 2, 64);
      pr_ = __shfl_xor(re, m, 64); pi_ = __shfl_xor(im, m, 64);
      nr = fmaf(c, re, s * pi_);
      ni = fmaf(c, im, -s * pr_);
      re = nr; im = ni;
      const int tm = 1 << (3 - ((qi + 1) & 3));   // <16: in-group
      float fr = __shfl_xor(re, tm, 64), fi = __shfl_xor(im, tm, 64);
      if (b) { re = fr; im = fi; }
    }
    float pr2 = re * re + im * im;
    float z0 = ((l >> 3) & 1) ? -pr2 : pr2;
    float z1 = ((l >> 2) & 1) ? -pr2 : pr2;
    float z2 = ((l >> 1) & 1) ? -pr2 : pr2;
    float z3 = (l & 1) ? -pr2 : pr2;
    #pragma unroll
    for (int off = 8; off >= 1; off >>= 1) {      // in-group reductions
      z0 += __shfl_xor(z0, off, 64);
      z1 += __shfl_xor(z1, off, 64);
      z2 += __shfl_xor(z2, off, 64);
      z3 += __shfl_xor(z3, off, 64);
    }
    float as0 = 0.f, as1 = 0.f, as2 = 0.f, as3 = 0.f;
    float aq0 = 0.f, aq1 = 0.f, aq2 = 0.f, aq3 = 0.f;
    if (l == 0) {                     // lanes 0,16,32,48: one sample each
      float o0 = fmaf(rw[0],  z0, fmaf(rw[1],  z1, fmaf(rw[2],  z2, fmaf(rw[3],  z3, rb[0]))));
      float o1 = fmaf(rw[4],  z0, fmaf(rw[5],  z1, fmaf(rw[6],  z2, fmaf(rw[7],  z3, rb[1]))));
      float o2 = fmaf(rw[8],  z0, fmaf(rw[9],  z1, fmaf(rw[10], z2, fmaf(rw[11], z3, rb[2]))));
      float o3 = fmaf(rw[12], z0, fmaf(rw[13], z1, fmaf(rw[14], z2, fmaf(rw[15], z3, rb[3]))));
      *(float4*)(pre + (size_t)(base + s2) * 4) = make_float4(o0, o1, o2, o3);
      as0 = o0; aq0 = o0 * o0;
      as1 = o1; aq1 = o1 * o1;
      as2 = o2; aq2 = o2 * o2;
      as3 = o3; aq3 = o3 * o3;
    }
    #pragma unroll
    for (int off = 32; off >= 16; off >>= 1) {
      as0 += __shfl_down(as0, off, 64); aq0 += __shfl_down(aq0, off, 64);
      as1 += __shfl_down(as1, off, 64); aq1 += __shfl_down(aq1, off, 64);
      as2 += __shfl_down(as2, off, 64); aq2 += __shfl_down(aq2, off, 64);
      as3 += __shfl_down(as3, off, 64); aq3 += __shfl_down(aq3, off, 64);
    }
    if (lane == 0) {
      s_red[w][0] = as0; s_red[w][4] = aq0;
      s_red[w][1] = as1; s_red[w][5] = aq1;
      s_red[w][2] = as2; s_red[w][6] = aq2;
      s_red[w][3] = as3; s_red[w][7] = aq3;
    }
  }
  __syncthreads();
  if (tid < 8) {
    float v = s_red[0][tid] + s_red[1][tid] + s_red[2][tid] + s_red[3][tid];
    atomicAdd(&stats[tid], v);
  }
}

__global__ __launch_bounds__(256) void qnat_bn(
    float* __restrict__ pre,
    const float* __restrict__ stats,
    const float* __restrict__ bnw,
    const float* __restrict__ bnb)
{
  int idx = blockIdx.x * 256 + threadIdx.x;
  int c = idx & 3;
  float mean = stats[c] * (1.0f / BATCH);
  float ex2 = stats[4 + c] * (1.0f / BATCH);
  float var = ex2 - mean * mean;
  float inv = rsqrtf(var + 1e-5f);
  pre[idx] = (pre[idx] - mean) * inv * bnw[c] + bnb[c];
}

extern "C" void kernel_launch(void* const* d_in, const int* in_sizes, int n_in,
                              void* d_out, int out_size, void* d_ws, size_t ws_size,
                              hipStream_t stream) {
  const float* x   = (const float*)d_in[0];
  const float* w1  = (const float*)d_in[1];
  const float* b1  = (const float*)d_in[2];
  const float* w2  = (const float*)d_in[3];
  const float* b2  = (const float*)d_in[4];
  const float* plw = (const float*)d_in[5];
  const float* plb = (const float*)d_in[6];
  const float* rw  = (const float*)d_in[7];
  const float* rb  = (const float*)d_in[8];
  const float* bnw = (const float*)d_in[9];
  const float* bnb = (const float*)d_in[10];

  float* out   = (float*)d_out;
  float* stats = (float*)d_ws;

  hipMemsetAsync(stats, 0, 8 * sizeof(float), stream);
  qnat_fused<<<BATCH / 16, 256, 0, stream>>>(x, w1, b1, w2, b2, plw, plb, rw, rb, out, stats);
  qnat_bn<<<(BATCH * 4) / 256, 256, 0, stream>>>(out, stats, bnw, bnb);
}

// Round 8
// 129.805 us; speedup vs baseline: 1.0267x; 1.0095x over previous
//
#include <hip/hip_runtime.h>
#include <math.h>

#define BATCH 16384

typedef float v2f __attribute__((ext_vector_type(2)));
typedef unsigned short u16;
typedef __attribute__((ext_vector_type(8))) short short8;
typedef __attribute__((ext_vector_type(4))) float f32x4;

__device__ __forceinline__ v2f pk_fma(v2f a, v2f b, v2f c) {
  return __builtin_elementwise_fma(a, b, c);   // -> v_pk_fma_f32
}
__device__ __forceinline__ v2f pk_max(v2f a, v2f b) {
  return __builtin_elementwise_max(a, b);      // -> v_pk_max_f32
}

// RNE-pack two floats into a bf16 pair (lo -> low16, hi -> high16)
__device__ __forceinline__ unsigned bf2(float lo, float hi) {
  unsigned a = __float_as_uint(lo);
  unsigned b = __float_as_uint(hi);
  a = (a + 0x7fffu + ((a >> 16) & 1u)) >> 16;
  b = (b + 0x7fffu + ((b >> 16) & 1u)) & 0xffff0000u;
  return a | b;
}

// single-inst RNE pack: dst.lo16 = bf16(lo), dst.hi16 = bf16(hi)
__device__ __forceinline__ unsigned cvtpk(float lo, float hi) {
  unsigned r;
  asm("v_cvt_pk_bf16_f32 %0, %1, %2" : "=v"(r) : "v"(lo), "v"(hi));
  return r;
}

// v19 = exact v16 revert (best measured: dur_us 130.37, fused 42.0us).
// Final state. Session ledger of falsified theories: occupancy/TLP (v12 spill
// cliff via min-waves hint; v13 2-samp/wave 32w/CU ceiling, VALUBusy flat;
// v17 VGPR crept 80, 6 barriers serialize; v18 wave-private no-barrier
// low-LDS = neutral), I-cache thrash (v14 rolled loop = exact null),
// residency tail (v18 had none, didn't beat v16). Only instruction removal
// paid, ~1:1: v15 linear->MFMA (+0.27% MfmaUtil), v16 conv2->MFMA (-5.4us,
// conflicts 2.36M->0.64M). conv1 is at pk_fma MAC floor; conv2 + linear on
// the otherwise-idle matrix pipe; remaining stage-2 shuffle-chain ideas are
// sub-noise (<2us, bench noise +-1.5us). Practical plateau: VALU 41% / HBM 7%
// / latency-structure-bound at 16 waves/CU (VGPR 72 band), total ~65% fixed
// harness overhead.
__global__ __launch_bounds__(256) void qnat_fused(
    const float* __restrict__ x,    // (B,1,28,28)
    const float* __restrict__ w1,   // (4,1,3,3)  uniform -> s_load
    const float* __restrict__ b1,   // (4,)
    const float* __restrict__ w2,   // (4,4,3,3)  uniform -> s_load
    const float* __restrict__ b2,   // (4,)
    const float* __restrict__ plw,  // (16,196)
    const float* __restrict__ plb,  // (16,)
    const float* __restrict__ rw,   // (4,4)
    const float* __restrict__ rb,   // (4,)
    float* __restrict__ pre,        // (B,4) pre-BN output (in d_out)
    float* __restrict__ stats)      // [8] {sum_c, sumsq_c}
{
  // block-shared pooled conv1 output, bf16: per sample 4ci x 16x16 (y,x each
  // offset +1; rows/cols 0,15 zero pads), sample stride 513 dwords (odd ->
  // 16-sample fragment gather hits each bank 2x = free).
  __shared__ __align__(16) unsigned h1sh[16 * 513];
  // block-shared h2 (bf16): 16 slots; 196 data + pad to 224 + 8 -> stride 232
  __shared__ __align__(16) u16 h2b[16][232];
  // transposed bf16 plw in B-fragment layout; rows 25..27 zero (K pad 224)
  __shared__ __align__(16) uint4 plw_tb[28 * 16];
  // conv2 B matrix (64K x 16N) bf16: B[(ci*16+dy*4+dx)*16 + (co*4+sy*2+sx)]
  __shared__ __align__(16) u16 b2f[64 * 16];
  __shared__ float s_red[4][8];

  const int tid = threadIdx.x;
  const int w = tid >> 6;
  const int lane = tid & 63;
  const int base = (blockIdx.x * 4 + w) * 4;    // first of 4 samples

  // ---- stage plw -> plw_tb (bf16, transposed), once per block ----
  #pragma unroll
  for (int j = 0; j < 2; j++) {
    int s = tid + 256 * j;
    if (s < 448) {
      int tp = s >> 4;                // 0..27
      int k2 = s & 15;
      uint4 v = make_uint4(0u, 0u, 0u, 0u);
      if (tp < 25) {
        const float4* pr = (const float4*)(plw + k2 * 196);
        float4 a = pr[2 * tp];
        float4 b = (tp < 24) ? pr[2 * tp + 1] : make_float4(0.f, 0.f, 0.f, 0.f);
        v = make_uint4(bf2(a.x, a.y), bf2(a.z, a.w),
                       bf2(b.x, b.y), bf2(b.z, b.w));
      }
      plw_tb[s] = v;
    }
  }

  // ---- build conv2 B matrix (1024 entries, 4/thread) ----
  #pragma unroll
  for (int j = 0; j < 4; j++) {
    int e = tid + 256 * j;            // e = k*16 + n
    int kk = e >> 4, n = e & 15;
    int ci = kk >> 4, dy = (kk >> 2) & 3, dx = kk & 3;
    int co = n >> 2, sy = (n >> 1) & 1, sx = n & 1;
    int ry = dy - sy, rx = dx - sx;
    float v = 0.0f;
    if (ry >= 0 && ry < 3 && rx >= 0 && rx < 3)
      v = w2[((co * 4 + ci) * 3 + ry) * 3 + rx];
    b2f[e] = (u16)bf2(v, 0.0f);
  }

  // ---- zero h1sh (pads persist; data overwritten) + h2b fully ----
  {
    uint4 z4 = make_uint4(0u, 0u, 0u, 0u);
    uint4* hz = (uint4*)h1sh;                   // 16*513 u32 = 2052 uint4
    #pragma unroll
    for (int t = 0; t < 9; t++) {
      int p = tid + 256 * t;
      if (p < 2052) hz[p] = z4;
    }
    uint4* hz2 = (uint4*)h2b;                   // 16*232 shorts = 464 uint4
    #pragma unroll
    for (int t = 0; t < 2; t++) {
      int p = tid + 256 * t;
      if (p < 464) hz2[p] = z4;
    }
  }
  __syncthreads();   // plw_tb, b2f, zeros visible

  const int i = lane >> 2;            // conv1: pooled row 0..13
  const int q = lane & 3;             // conv1: col quad
  const bool c1act = lane < 56;

  // prefetch buffers for conv1 windows (cols 8q-1 .. 8q+8 fully covered)
  float4 pfa[4], pfb[4];
  float pe0[4], pe1[4];
  #pragma unroll
  for (int r = 0; r < 4; r++) {
    pfa[r] = make_float4(0,0,0,0); pfb[r] = make_float4(0,0,0,0);
    pe0[r] = 0.0f; pe1[r] = 0.0f;
  }

  if (c1act) {
    const float* xb = x + (size_t)base * 784;
    #pragma unroll
    for (int r = 0; r < 4; r++) {
      int row = 2 * i - 1 + r;
      if (0 <= row && row < 28) {
        const float* rp = xb + row * 28;
        pfa[r] = *(const float4*)(rp + 8 * q);
        if (q > 0) pe0[r] = rp[8 * q - 1];
        if (q < 3) {
          pfb[r] = *(const float4*)(rp + 8 * q + 4);
          pe1[r] = rp[8 * q + 8];
        }
      }
    }
  }

  // ================= stage 1a: conv1 for 4 samples -> h1sh (bf16) ============
  #pragma unroll 1
  for (int it = 0; it < 4; ++it) {
    if (c1act) {
      float win[4][10];               // win[r][k] <-> input col 8q-1+k
      #pragma unroll
      for (int r = 0; r < 4; r++) {
        win[r][0] = pe0[r];
        win[r][1] = pfa[r].x; win[r][2] = pfa[r].y;
        win[r][3] = pfa[r].z; win[r][4] = pfa[r].w;
        win[r][5] = pfb[r].x; win[r][6] = pfb[r].y;
        win[r][7] = pfb[r].z; win[r][8] = pfb[r].w;
        win[r][9] = pe1[r];
      }
      // prefetch next sample's rows while conv1 FMAs run
      if (it != 3) {
        const float* xn = x + (size_t)(base + it + 1) * 784;
        #pragma unroll
        for (int r = 0; r < 4; r++) {
          int row = 2 * i - 1 + r;
          pfa[r] = make_float4(0,0,0,0);
          pfb[r] = make_float4(0,0,0,0);
          pe0[r] = 0.0f; pe1[r] = 0.0f;
          if (0 <= row && row < 28) {
            const float* rp = xn + row * 28;
            pfa[r] = *(const float4*)(rp + 8 * q);
            if (q > 0) pe0[r] = rp[8 * q - 1];
            if (q < 3) {
              pfb[r] = *(const float4*)(rp + 8 * q + 4);
              pe1[r] = rp[8 * q + 8];
            }
          }
        }
      }
      v2f P[4][9];
      #pragma unroll
      for (int r = 0; r < 4; r++)
        #pragma unroll
        for (int k = 0; k < 9; k++) P[r][k] = (v2f){win[r][k], win[r][k + 1]};

      // u16 base into h1sh for this sample: stride 1026 u16/sample
      u16* hs = (u16*)h1sh + (4 * w + it) * 1026 + (i + 1) * 16 + 4 * q;
      #pragma unroll
      for (int c = 0; c < 4; c++) {
        const float* wc = w1 + c * 9;
        const v2f bias2 = (v2f){b1[c], b1[c]};
        v2f a0[4], a1[4];
        #pragma unroll
        for (int jj = 0; jj < 4; jj++) { a0[jj] = bias2; a1[jj] = bias2; }
        #pragma unroll
        for (int dy = 0; dy < 3; dy++)
          #pragma unroll
          for (int dx = 0; dx < 3; dx++) {
            const float wv = wc[dy * 3 + dx];
            const v2f wvv = (v2f){wv, wv};
            #pragma unroll
            for (int jj = 0; jj < 4; jj++) {
              a0[jj] = pk_fma(P[dy][2 * jj + dx],     wvv, a0[jj]);
              a1[jj] = pk_fma(P[dy + 1][2 * jj + dx], wvv, a1[jj]);
            }
          }
        float m[4];
        #pragma unroll
        for (int jj = 0; jj < 4; jj++) {
          v2f mm = pk_max(a0[jj], a1[jj]);
          m[jj] = fmaxf(fmaxf(mm.x, mm.y), 0.0f);
        }
        u16* p = hs + c * 256;        // stored cols 4q+1 .. 4q+4 (x offset +1)
        p[1] = (u16)cvtpk(m[0], m[0]);
        if (q < 3) {
          *(unsigned*)(p + 2) = cvtpk(m[1], m[2]);   // even u16 idx -> 4B align
          p[4] = (u16)cvtpk(m[3], m[3]);
        } else {
          p[2] = (u16)cvtpk(m[1], m[1]);
        }
      }
    }
  }
  __syncthreads();   // h1sh complete for all 16 samples

  // ======== stage 1b: conv2 + relu + pool via MFMA -> h2b (bf16) ============
  {
    const int n = lane & 15;          // A row = sample, B/C col = (co,sy,sx)
    const int g = lane >> 4;          // k-group
    // preload B fragments (k = 32*kt + 8g + j)
    short8 bfr0, bfr1;
    #pragma unroll
    for (int j = 0; j < 8; j++) {
      bfr0[j] = (short)b2f[(8 * g + j) * 16 + n];
      bfr1[j] = (short)b2f[(32 + 8 * g + j) * 16 + n];
    }
    const float b2v = b2[n >> 2];
    const int ci0 = g >> 1;
    const int dy0 = 2 * (g & 1);
    const int dbase = n * 513 + ci0 * 128 + dy0 * 8;   // dwords
    const unsigned* hp = h1sh;

    #pragma unroll 2
    for (int t = 0; t < 13; t++) {
      int p = 4 * t + w;              // wave-strided positions
      if (p < 49) {
        int i2 = (p * 9363) >> 16;    // p/7
        int j2 = p - 7 * i2;
        int d = dbase + i2 * 16 + j2;
        f32x4 acc = {0.f, 0.f, 0.f, 0.f};
        {
          unsigned A0 = hp[d],       A1 = hp[d + 1];
          unsigned A2 = hp[d + 8],   A3 = hp[d + 9];
          short8 av = __builtin_bit_cast(short8, make_uint4(A0, A1, A2, A3));
          acc = __builtin_amdgcn_mfma_f32_16x16x32_bf16(av, bfr0, acc, 0, 0, 0);
        }
        {
          unsigned A0 = hp[d + 256], A1 = hp[d + 257];
          unsigned A2 = hp[d + 264], A3 = hp[d + 265];
          short8 av = __builtin_bit_cast(short8, make_uint4(A0, A1, A2, A3));
          acc = __builtin_amdgcn_mfma_f32_16x16x32_bf16(av, bfr1, acc, 0, 0, 0);
        }
        // pool over subpos: cols n^1 (sx), n^2 (sy) -> lanes lane^1, lane^2
        float r0 = acc[0], r1 = acc[1], r2 = acc[2], r3 = acc[3];
        r0 = fmaxf(r0, __shfl_xor(r0, 1, 64)); r0 = fmaxf(r0, __shfl_xor(r0, 2, 64));
        r1 = fmaxf(r1, __shfl_xor(r1, 1, 64)); r1 = fmaxf(r1, __shfl_xor(r1, 2, 64));
        r2 = fmaxf(r2, __shfl_xor(r2, 1, 64)); r2 = fmaxf(r2, __shfl_xor(r2, 2, 64));
        r3 = fmaxf(r3, __shfl_xor(r3, 1, 64)); r3 = fmaxf(r3, __shfl_xor(r3, 2, 64));
        if ((lane & 3) == 0) {
          int co = n >> 2;
          u16* hq = &h2b[4 * g][49 * co + p];
          float v0 = fmaxf(r0 + b2v, 0.0f);
          float v1 = fmaxf(r1 + b2v, 0.0f);
          float v2 = fmaxf(r2 + b2v, 0.0f);
          float v3 = fmaxf(r3 + b2v, 0.0f);
          hq[0]       = (u16)cvtpk(v0, v0);   // sample 4g+0
          hq[232]     = (u16)cvtpk(v1, v1);   // sample 4g+1
          hq[464]     = (u16)cvtpk(v2, v2);   // sample 4g+2
          hq[696]     = (u16)cvtpk(v3, v3);   // sample 4g+3
        }
      }
    }
  }
  __syncthreads();   // h2b complete for all 16 slots

  // ============ stage 2: MFMA linear + circuit for all 4 samples ============
  const int s2 = lane >> 4;           // sample slot 0..3 (within wave)
  const int k = lane & 15;            // param index / amp index

  // ---- linear: 16x224 @ 224x16 bf16 GEMM, 7 MFMA, all waves redundant ----
  float cv, sv;
  {
    const int arow = lane & 15;       // A row = block sample slot, B col = param
    const int kg = lane >> 4;         // k-group 0..3 (8 bf16 each)
    const short8* ha = (const short8*)&h2b[arow][0];    // 29 short8 per slot
    const short8* hbw = (const short8*)plw_tb;
    f32x4 acc = {0.f, 0.f, 0.f, 0.f};
    #pragma unroll
    for (int kt = 0; kt < 7; kt++) {
      short8 av = ha[4 * kt + kg];
      short8 bv = hbw[(4 * kt + kg) * 16 + arow];
      acc = __builtin_amdgcn_mfma_f32_16x16x32_bf16(av, bv, acc, 0, 0, 0);
    }
    // C[row=4*(l>>4)+reg][col=l&15]; wave w needs rows 4w..4w+3 -> quadrant w.
    const int srcl = 16 * w + k;      // lane holding C[4w+*][k]
    float c0 = __shfl(acc[0], srcl, 64);
    float c1 = __shfl(acc[1], srcl, 64);
    float c2 = __shfl(acc[2], srcl, 64);
    float c3 = __shfl(acc[3], srcl, 64);
    float pv = (s2 & 2) ? ((s2 & 1) ? c3 : c2) : ((s2 & 1) ? c1 : c0);
    pv += plb[k];
    __sincosf(pv * 0.5f, &sv, &cv);
  }

  // ---- 4-qubit circuit: 4 samples in parallel on 16-lane groups ----
  {
    const int l = k;                  // amp index within group
    const int gb = lane & 48;         // group base for param broadcasts
    float re = (l == 0) ? 1.0f : 0.0f;
    float im = 0.0f;
    #pragma unroll
    for (int qi = 0; qi < 4; qi++) {
      const int beta = 3 - qi;
      const int m = 1 << beta;        // <16: shfl_xor stays in group
      const int b = (l >> beta) & 1;
      float c = __shfl(cv, gb + 4 * qi, 64), s = __shfl(sv, gb + 4 * qi, 64);
      float pr_ = __shfl_xor(re, m, 64), pi_ = __shfl_xor(im, m, 64);
      float sg = b ? s : -s;
      re = fmaf(c, re, sg * pr_);
      im = fmaf(c, im, sg * pi_);
      c = __shfl(cv, gb + 4 * qi + 1, 64); s = __shfl(sv, gb + 4 * qi + 1, 64);
      float sz = b ? s : -s;
      float nr = c * re - sz * im;
      float ni = c * im + sz * re;
      re = nr; im = ni;
      c = __shfl(cv, gb + 4 * qi + 2, 64); s = __shfl(sv, gb + 4 * qi + 2, 64);
      pr_ = __shfl_xor(re, m, 64); pi_ = __shfl_xor(im, m, 64);
      nr = fmaf(c, re, s * pi_);
      ni = fmaf(c, im, -s * pr_);
      re = nr; im = ni;
      const int tm = 1 << (3 - ((qi + 1) & 3));   // <16: in-group
      float fr = __shfl_xor(re, tm, 64), fi = __shfl_xor(im, tm, 64);
      if (b) { re = fr; im = fi; }
    }
    float pr2 = re * re + im * im;
    float z0 = ((l >> 3) & 1) ? -pr2 : pr2;
    float z1 = ((l >> 2) & 1) ? -pr2 : pr2;
    float z2 = ((l >> 1) & 1) ? -pr2 : pr2;
    float z3 = (l & 1) ? -pr2 : pr2;
    #pragma unroll
    for (int off = 8; off >= 1; off >>= 1) {      // in-group reductions
      z0 += __shfl_xor(z0, off, 64);
      z1 += __shfl_xor(z1, off, 64);
      z2 += __shfl_xor(z2, off, 64);
      z3 += __shfl_xor(z3, off, 64);
    }
    float as0 = 0.f, as1 = 0.f, as2 = 0.f, as3 = 0.f;
    float aq0 = 0.f, aq1 = 0.f, aq2 = 0.f, aq3 = 0.f;
    if (l == 0) {                     // lanes 0,16,32,48: one sample each
      float o0 = fmaf(rw[0],  z0, fmaf(rw[1],  z1, fmaf(rw[2],  z2, fmaf(rw[3],  z3, rb[0]))));
      float o1 = fmaf(rw[4],  z0, fmaf(rw[5],  z1, fmaf(rw[6],  z2, fmaf(rw[7],  z3, rb[1]))));
      float o2 = fmaf(rw[8],  z0, fmaf(rw[9],  z1, fmaf(rw[10], z2, fmaf(rw[11], z3, rb[2]))));
      float o3 = fmaf(rw[12], z0, fmaf(rw[13], z1, fmaf(rw[14], z2, fmaf(rw[15], z3, rb[3]))));
      *(float4*)(pre + (size_t)(base + s2) * 4) = make_float4(o0, o1, o2, o3);
      as0 = o0; aq0 = o0 * o0;
      as1 = o1; aq1 = o1 * o1;
      as2 = o2; aq2 = o2 * o2;
      as3 = o3; aq3 = o3 * o3;
    }
    #pragma unroll
    for (int off = 32; off >= 16; off >>= 1) {
      as0 += __shfl_down(as0, off, 64); aq0 += __shfl_down(aq0, off, 64);
      as1 += __shfl_down(as1, off, 64); aq1 += __shfl_down(aq1, off, 64);
      as2 += __shfl_down(as2, off, 64); aq2 += __shfl_down(aq2, off, 64);
      as3 += __shfl_down(as3, off, 64); aq3 += __shfl_down(aq3, off, 64);
    }
    if (lane == 0) {
      s_red[w][0] = as0; s_red[w][4] = aq0;
      s_red[w][1] = as1; s_red[w][5] = aq1;
      s_red[w][2] = as2; s_red[w][6] = aq2;
      s_red[w][3] = as3; s_red[w][7] = aq3;
    }
  }
  __syncthreads();
  if (tid < 8) {
    float v = s_red[0][tid] + s_red[1][tid] + s_red[2][tid] + s_red[3][tid];
    atomicAdd(&stats[tid], v);
  }
}

__global__ __launch_bounds__(256) void qnat_bn(
    float* __restrict__ pre,
    const float* __restrict__ stats,
    const float* __restrict__ bnw,
    const float* __restrict__ bnb)
{
  int idx = blockIdx.x * 256 + threadIdx.x;
  int c = idx & 3;
  float mean = stats[c] * (1.0f / BATCH);
  float ex2 = stats[4 + c] * (1.0f / BATCH);
  float var = ex2 - mean * mean;
  float inv = rsqrtf(var + 1e-5f);
  pre[idx] = (pre[idx] - mean) * inv * bnw[c] + bnb[c];
}

extern "C" void kernel_launch(void* const* d_in, const int* in_sizes, int n_in,
                              void* d_out, int out_size, void* d_ws, size_t ws_size,
                              hipStream_t stream) {
  const float* x   = (const float*)d_in[0];
  const float* w1  = (const float*)d_in[1];
  const float* b1  = (const float*)d_in[2];
  const float* w2  = (const float*)d_in[3];
  const float* b2  = (const float*)d_in[4];
  const float* plw = (const float*)d_in[5];
  const float* plb = (const float*)d_in[6];
  const float* rw  = (const float*)d_in[7];
  const float* rb  = (const float*)d_in[8];
  const float* bnw = (const float*)d_in[9];
  const float* bnb = (const float*)d_in[10];

  float* out   = (float*)d_out;
  float* stats = (float*)d_ws;

  hipMemsetAsync(stats, 0, 8 * sizeof(float), stream);
  qnat_fused<<<BATCH / 16, 256, 0, stream>>>(x, w1, b1, w2, b2, plw, plb, rw, rb, out, stats);
  qnat_bn<<<(BATCH * 4) / 256, 256, 0, stream>>>(out, stats, bnw, bnb);
}